// Round 5
// baseline (937.564 us; speedup 1.0000x reference)
//
#include <hip/hip_runtime.h>
#include <hip/hip_bf16.h>

typedef __attribute__((ext_vector_type(8))) short short8;
typedef __attribute__((ext_vector_type(4))) float f32x4;

// B=32, C=64, N=4096, K=2049, modes=64
constexpr int NSEQ  = 4096;
constexpr int MROWS = 2049;
constexpr int MPAD  = 2176;   // 17 * 128
constexpr int KHT   = 2049;
constexpr int TABST = 2080;
constexpr int BATCH = 32;
constexpr int SLABS = 512;    // 4096 / 8
constexpr float TPI = 6.283185307179586f;   // fp32(2*pi), matches reference chain

constexpr size_t PLANE_USH = (size_t)SLABS * MPAD * 8;     // 8,912,896 shorts/plane

// ws layout in float units (total ~73.4 MB)
constexpr size_t ASPL_FLT = 3 * PLANE_USH / 2;             // 13,369,344
constexpr size_t COSP_OFF = ASPL_FLT;
constexpr size_t COSP_SZ  = (size_t)MPAD * 2048;           // 4,456,448
constexpr size_t XH_OFF   = COSP_OFF + COSP_SZ;
constexpr size_t XH_SZ    = (size_t)64 * 2048;
constexpr size_t TAB_OFF  = XH_OFF + XH_SZ;
constexpr size_t TAB_SZ   = (size_t)128 * TABST;
constexpr size_t OH_OFF   = TAB_OFF + TAB_SZ;

// ---- 3-way bf16 split via bit-truncation: v = f(h0)+f(h1)+f(h2) + O(2^-24 |v|)
// subtractions are exact (low-bit removal), so planes sum to v up to trunc of r2.
__device__ __forceinline__ void split3t(float v, short &h0, short &h1, short &h2) {
  unsigned u  = __builtin_bit_cast(unsigned, v);
  unsigned u0 = u & 0xFFFF0000u;
  float f0 = __builtin_bit_cast(float, u0);
  float r1 = v - f0;                       // exact
  unsigned u1 = __builtin_bit_cast(unsigned, r1) & 0xFFFF0000u;
  float f1 = __builtin_bit_cast(float, u1);
  float r2 = r1 - f1;                      // exact
  h0 = (short)(u0 >> 16);
  h1 = (short)(u1 >> 16);
  h2 = (short)(__builtin_bit_cast(unsigned, r2) >> 16);
}

__device__ __forceinline__ void gl_lds16(const short* g, short* s) {
  __builtin_amdgcn_global_load_lds((const __attribute__((address_space(1))) void*)g,
                                   (__attribute__((address_space(3))) void*)s, 16, 0, 0);
}

// ---------------- prep: cas_N split planes, slab-major [k/8][row][8] --------
__global__ __launch_bounds__(256) void prep_A(short* __restrict__ Aq) {
  int row = blockIdx.x * 256 + threadIdx.x;
  if (row >= MPAD) return;
  int slab = blockIdx.y;
  short8 o0, o1, o2;
  float t1 = TPI * (float)row;             // fl32(2pi*n), n = row first!
  #pragma unroll
  for (int e = 0; e < 8; ++e) {
    float v = 0.0f;
    if (row < MROWS) {
      float t2  = t1 * (float)(slab * 8 + e);   // fl32(t1*p)
      float arg = t2 * (1.0f / 4096.0f);        // exact pow2 divide
      v = cosf(arg) + sinf(arg);
    }
    short h0, h1, h2; split3t(v, h0, h1, h2);
    o0[e] = h0; o1[e] = h1; o2[e] = h2;
  }
  size_t base = (size_t)slab * (MPAD * 8) + (size_t)row * 8;
  *(short8*)(Aq + base)                  = o0;
  *(short8*)(Aq + PLANE_USH + base)      = o1;
  *(short8*)(Aq + 2 * PLANE_USH + base)  = o2;
}

// ---------------- prep: cas_K sparse-column table, 1/K folded in ------------
__global__ __launch_bounds__(256) void prep_tab(float* __restrict__ tab) {
  int idx = blockIdx.x * 256 + threadIdx.x;
  if (idx >= 128 * TABST) return;
  int j  = idx / TABST;
  int np = idx - j * TABST;
  float v = 0.0f;
  if (np < KHT) {
    int c = j >> 1, b = j & 1;
    int pp = 32 * c + b;
    float t1  = TPI * (float)np;
    float t2  = t1 * (float)pp;
    float arg = t2 / 2049.0f;
    v = (cosf(arg) + sinf(arg)) * (1.0f / 2049.0f);
  }
  tab[idx] = v;
}

// ---------------- MFMA GEMM + fused cos(atan2) epilogue ---------------------
// 2-phase prefetch: As double-buffered (gl_lds issued 1 tile early), B loads
// issued 1 tile early into regs, split+ds_write after the post-MFMA barrier.
__global__ __launch_bounds__(256, 2) void gemm_mfma(const short* __restrict__ Aq,
                                                    const float* __restrict__ x,
                                                    float* __restrict__ cosp,
                                                    float* __restrict__ xh64) {
  __shared__ __align__(16) short As[2][3][4096];  // [buf][plane][slab*1024+row*8+e]
  __shared__ __align__(16) short Bs[3][4096];     // [plane][slab*1024 + j*8 + e]
  const int t    = threadIdx.x;
  const int lane = t & 63;
  const int w    = t >> 6;
  const int wr   = w >> 1, wc = w & 1;
  const int bm   = blockIdx.y * 128;
  const int c0   = blockIdx.x * 64;

  const int j    = t & 127;
  const int sA   = t >> 7;                 // slabs sA and sA+2
  const int cc   = c0 + (j >> 1);
  const int flip = j & 1;
  const int mm   = cc & 63;
  const float* xb = x + (cc >> 6) * 262144;
  const int bi0  = (sA * 128 + j) * 8;
  const int bi1  = ((sA + 2) * 128 + j) * 8;

  int aIdx[4], bIdx[4];
  #pragma unroll
  for (int f = 0; f < 4; ++f) {
    aIdx[f] = (lane >> 4) * 1024 + (wr * 64 + f * 16 + (lane & 15)) * 8;
    bIdx[f] = (lane >> 4) * 1024 + (wc * 64 + f * 16 + (lane & 15)) * 8;
  }

  f32x4 accM[4][4] = {};   // a0*b0 only
  f32x4 accL[4][4] = {};   // the 5 small products
  float breg[16];

  auto issueA = [&](int kt, int buf) {
    const int sg0 = kt << 2;
    #pragma unroll
    for (int i = 0; i < 6; ++i) {
      int q = w * 6 + i;                   // q = p*8 + s*2 + h
      int p = q >> 3, s = (q >> 1) & 3, h = q & 1;
      const short* gp = Aq + (size_t)p * PLANE_USH + (size_t)(sg0 + s) * (MPAD * 8)
                        + (size_t)(bm + h * 64 + lane) * 8;
      gl_lds16(gp, &As[buf][p][s * 1024 + h * 512]);
    }
  };
  auto issueB = [&](int kt) {
    #pragma unroll
    for (int tk = 0; tk < 2; ++tk) {
      int s  = (tk == 0) ? sA : sA + 2;
      int kb = kt * 32 + s * 8;
      int hi = (kb >> 6) << 12;
      int lo = ((kb & 63) << 6) + mm;
      int base = flip ? (hi + 4095 - lo) : (hi + lo);
      int step = flip ? -64 : 64;
      #pragma unroll
      for (int e = 0; e < 8; ++e) breg[tk * 8 + e] = xb[base + e * step];
    }
  };
  auto writeB = [&]() {
    #pragma unroll
    for (int tk = 0; tk < 2; ++tk) {
      short8 p0, p1, p2;
      #pragma unroll
      for (int e = 0; e < 8; ++e) {
        short h0, h1, h2; split3t(breg[tk * 8 + e], h0, h1, h2);
        p0[e] = h0; p1[e] = h1; p2[e] = h2;
      }
      int bi = (tk == 0) ? bi0 : bi1;
      *(short8*)&Bs[0][bi] = p0;
      *(short8*)&Bs[1][bi] = p1;
      *(short8*)&Bs[2][bi] = p2;
    }
  };
  auto compute = [&](int buf) {
    short8 fa0[4], fa1[4], fa2[4];
    #pragma unroll
    for (int f = 0; f < 4; ++f) {
      fa0[f] = *(const short8*)&As[buf][0][aIdx[f]];
      fa1[f] = *(const short8*)&As[buf][1][aIdx[f]];
      fa2[f] = *(const short8*)&As[buf][2][aIdx[f]];
    }
    __builtin_amdgcn_s_setprio(1);
    {
      short8 fb[4];
      #pragma unroll
      for (int f = 0; f < 4; ++f) fb[f] = *(const short8*)&Bs[0][bIdx[f]];
      #pragma unroll
      for (int fi = 0; fi < 4; ++fi)
        #pragma unroll
        for (int fj = 0; fj < 4; ++fj) {
          accM[fi][fj] = __builtin_amdgcn_mfma_f32_16x16x32_bf16(fa0[fi], fb[fj], accM[fi][fj], 0, 0, 0);
          accL[fi][fj] = __builtin_amdgcn_mfma_f32_16x16x32_bf16(fa1[fi], fb[fj], accL[fi][fj], 0, 0, 0);
          accL[fi][fj] = __builtin_amdgcn_mfma_f32_16x16x32_bf16(fa2[fi], fb[fj], accL[fi][fj], 0, 0, 0);
        }
    }
    {
      short8 fb[4];
      #pragma unroll
      for (int f = 0; f < 4; ++f) fb[f] = *(const short8*)&Bs[1][bIdx[f]];
      #pragma unroll
      for (int fi = 0; fi < 4; ++fi)
        #pragma unroll
        for (int fj = 0; fj < 4; ++fj) {
          accL[fi][fj] = __builtin_amdgcn_mfma_f32_16x16x32_bf16(fa0[fi], fb[fj], accL[fi][fj], 0, 0, 0);
          accL[fi][fj] = __builtin_amdgcn_mfma_f32_16x16x32_bf16(fa1[fi], fb[fj], accL[fi][fj], 0, 0, 0);
        }
    }
    {
      short8 fb[4];
      #pragma unroll
      for (int f = 0; f < 4; ++f) fb[f] = *(const short8*)&Bs[2][bIdx[f]];
      #pragma unroll
      for (int fi = 0; fi < 4; ++fi)
        #pragma unroll
        for (int fj = 0; fj < 4; ++fj)
          accL[fi][fj] = __builtin_amdgcn_mfma_f32_16x16x32_bf16(fa0[fi], fb[fj], accL[fi][fj], 0, 0, 0);
    }
    __builtin_amdgcn_s_setprio(0);
  };

  // prologue: stage tile 0
  issueA(0, 0);
  issueB(0);
  writeB();               // compiler inserts waits on the 16 B loads
  __syncthreads();        // drains vmcnt (As[0] ready) + lgkm (Bs ready)

  for (int kt = 0; kt < 128; ++kt) {
    int nb = kt + 1;
    if (nb < 128) { issueA(nb, nb & 1); issueB(nb); }  // fly during MFMA
    compute(kt & 1);
    __syncthreads();      // all waves done reading Bs; prefetch drained (old)
    if (nb < 128) writeB();
    __syncthreads();      // Bs(t+1) visible
  }

  // ---- epilogue: pair a (even j) with b (odd j) via lane-xor-1, fuse cosp ----
  #pragma unroll
  for (int fi = 0; fi < 4; ++fi) {
    int row0 = bm + wr * 64 + fi * 16 + ((lane >> 4) << 2);
    #pragma unroll
    for (int fj = 0; fj < 4; ++fj) {
      int jc = wc * 64 + fj * 16 + (lane & 15);
      int c  = c0 + (jc >> 1);
      #pragma unroll
      for (int r = 0; r < 4; ++r) {
        float v = accM[fi][fj][r] + accL[fi][fj][r];
        float o = __shfl_xor(v, 1, 64);
        float a = (lane & 1) ? o : v;
        float b = (lane & 1) ? v : o;
        float r2 = a * a + b * b;
        float cp = (r2 > 0.0f) ? (a / sqrtf(r2)) : 1.0f;   // cos(atan2(b,a))
        if ((lane & 1) == 0) {
          cosp[(size_t)(row0 + r) * 2048 + c] = cp;
          if (bm == 0 && wr == 0) xh64[(row0 + r) * 2048 + c] = a;  // rows 0..63
        }
      }
    }
  }
}

// ---------------- compl_mul: out_ht[b,o,m], modes=64 ------------------------
__global__ __launch_bounds__(256) void complmul(const float* __restrict__ xh64,
                                                const float* __restrict__ W,
                                                float* __restrict__ oh) {
  __shared__ float cl[64 * 65];
  const int t  = threadIdx.x;
  const int bq = blockIdx.y;
  const int og = blockIdx.x;
  #pragma unroll
  for (int e = 0; e < 16; ++e) {
    int idx = t + e * 256;
    int i = idx & 63, m = idx >> 6;
    cl[m * 65 + i] = xh64[m * 2048 + bq * 64 + i];
  }
  __syncthreads();
  const int m  = t & 63;
  const int o  = og * 4 + (t >> 6);
  const int mn = (64 - m) & 63;
  float s = 0.0f;
  for (int i = 0; i < 64; ++i) {
    float w  = W[i * 4096 + o * 64 + m];
    float wn = W[i * 4096 + o * 64 + mn];
    s += cl[m * 65 + i] * (w + wn) + cl[mn * 65 + i] * (w - wn);
  }
  oh[bq * 4096 + o * 64 + m] = 0.5f * s;
}

// ---------------- final: xi (sparse 64-term) * cosp -------------------------
__global__ __launch_bounds__(256) void final_k(const float* __restrict__ cosp,
                                               const float* __restrict__ tab,
                                               const float* __restrict__ oh,
                                               float* __restrict__ out) {
  __shared__ float tl[128 * 32];
  __shared__ float ol[64 * 64];
  const int t  = threadIdx.x;
  const int d  = blockIdx.y;
  const int n0 = blockIdx.x * 32;
  #pragma unroll
  for (int e = 0; e < 16; ++e) {
    int idx = t + e * 256;
    tl[idx] = tab[(idx >> 5) * TABST + n0 + (idx & 31)];
  }
  #pragma unroll
  for (int e = 0; e < 16; ++e) {
    int idx = t + e * 256;
    ol[idx] = oh[d * 4096 + idx];
  }
  __syncthreads();
  const int mp   = t & 63;
  const int nsub = t >> 6;

  float ohreg[64];
  #pragma unroll
  for (int c = 0; c < 64; ++c)
    ohreg[c] = ol[c * 64 + ((mp - c) & 63)];

  float acc[8] = {};
  #pragma unroll
  for (int c = 0; c < 64; ++c) {
    const float* tp = &tl[(2 * c + (c > mp ? 1 : 0)) * 32 + nsub * 8];
    float tv[8];
    *(float4*)&tv[0] = *(const float4*)tp;
    *(float4*)&tv[4] = *(const float4*)(tp + 4);
    #pragma unroll
    for (int q = 0; q < 8; ++q) acc[q] += tv[q] * ohreg[c];
  }
  #pragma unroll
  for (int q = 0; q < 8; ++q) {
    int np = n0 + nsub * 8 + q;
    if (np < KHT) {
      float cp = cosp[(size_t)np * 2048 + d * 64 + mp];
      out[d * 131136 + mp * 2049 + np] = acc[q] * cp;
    }
  }
}

extern "C" void kernel_launch(void* const* d_in, const int* in_sizes, int n_in,
                              void* d_out, int out_size, void* d_ws, size_t ws_size,
                              hipStream_t stream) {
  const float* x = (const float*)d_in[0];     // (32, 64, 4096) f32
  const float* W = (const float*)d_in[1];     // (64, 64, 64) f32
  float* out = (float*)d_out;                 // (32, 64, 2049) f32
  float* ws  = (float*)d_ws;

  short* Aq    = (short*)ws;
  float* cospB = ws + COSP_OFF;
  float* xh64  = ws + XH_OFF;
  float* tab   = ws + TAB_OFF;
  float* oh    = ws + OH_OFF;

  prep_A   <<<dim3((MPAD + 255) / 256, SLABS), dim3(256), 0, stream>>>(Aq);
  prep_tab <<<dim3((128 * TABST + 255) / 256), dim3(256), 0, stream>>>(tab);
  gemm_mfma<<<dim3(32, 17), dim3(256), 0, stream>>>(Aq, x, cospB, xh64);
  complmul <<<dim3(16, BATCH), dim3(256), 0, stream>>>(xh64, W, oh);
  final_k  <<<dim3(65, BATCH), dim3(256), 0, stream>>>(cospB, tab, oh, out);
}

// Round 7
// 849.513 us; speedup vs baseline: 1.1036x; 1.1036x over previous
//
#include <hip/hip_runtime.h>
#include <hip/hip_bf16.h>

typedef __attribute__((ext_vector_type(8))) short short8;
typedef __attribute__((ext_vector_type(4))) float f32x4;
typedef __attribute__((ext_vector_type(4))) int  i32x4;

// B=32, C=64, N=4096, K=2049, modes=64
constexpr int NSEQ  = 4096;
constexpr int MROWS = 2049;
constexpr int MPAD  = 2176;   // 17 * 128
constexpr int KHT   = 2049;
constexpr int TABST = 2080;
constexpr int BATCH = 32;
constexpr int SLABS = 512;    // 4096 / 8
constexpr float TPI = 6.283185307179586f;   // fp32(2*pi), matches reference chain

constexpr size_t PLANE_USH = (size_t)SLABS * MPAD * 8;     // 8,912,896 shorts/plane

// ws layout in float units (unchanged from round 4, ~73.4 MB)
constexpr size_t ASPL_FLT = 3 * PLANE_USH / 2;             // 13,369,344
constexpr size_t COSP_OFF = ASPL_FLT;
constexpr size_t COSP_SZ  = (size_t)MPAD * 2048;           // 4,456,448
constexpr size_t XH_OFF   = COSP_OFF + COSP_SZ;
constexpr size_t XH_SZ    = (size_t)64 * 2048;
constexpr size_t TAB_OFF  = XH_OFF + XH_SZ;
constexpr size_t TAB_SZ   = (size_t)128 * TABST;
constexpr size_t OH_OFF   = TAB_OFF + TAB_SZ;

// ---- 3-way bf16 split via bit-truncation: exact decomposition of fp32 ------
__device__ __forceinline__ void split3t(float v, short &h0, short &h1, short &h2) {
  unsigned u  = __builtin_bit_cast(unsigned, v);
  unsigned u0 = u & 0xFFFF0000u;
  float f0 = __builtin_bit_cast(float, u0);
  float r1 = v - f0;                       // exact
  unsigned u1 = __builtin_bit_cast(unsigned, r1) & 0xFFFF0000u;
  float f1 = __builtin_bit_cast(float, u1);
  float r2 = r1 - f1;                      // exact
  h0 = (short)(u0 >> 16);
  h1 = (short)(u1 >> 16);
  h2 = (short)(__builtin_bit_cast(unsigned, r2) >> 16);
}

__device__ __forceinline__ void gl_lds16(const short* g, short* s) {
  __builtin_amdgcn_global_load_lds((const __attribute__((address_space(1))) void*)g,
                                   (__attribute__((address_space(3))) void*)s, 16, 0, 0);
}

__device__ __forceinline__ int rot16(int x) {
  return (int)(((unsigned)x >> 16) | ((unsigned)x << 16));
}

// ---------------- prep: cas_N split planes, slab-major [k/8][row][8] --------
__global__ __launch_bounds__(256) void prep_A(short* __restrict__ Aq) {
  int row = blockIdx.x * 256 + threadIdx.x;
  if (row >= MPAD) return;
  int slab = blockIdx.y;
  short8 o0, o1, o2;
  float t1 = TPI * (float)row;             // fl32(2pi*n), n = row first!
  #pragma unroll
  for (int e = 0; e < 8; ++e) {
    float v = 0.0f;
    if (row < MROWS) {
      float t2  = t1 * (float)(slab * 8 + e);   // fl32(t1*p)
      float arg = t2 * (1.0f / 4096.0f);        // exact pow2 divide
      v = cosf(arg) + sinf(arg);
    }
    short h0, h1, h2; split3t(v, h0, h1, h2);
    o0[e] = h0; o1[e] = h1; o2[e] = h2;
  }
  size_t base = (size_t)slab * (MPAD * 8) + (size_t)row * 8;
  *(short8*)(Aq + base)                  = o0;
  *(short8*)(Aq + PLANE_USH + base)      = o1;
  *(short8*)(Aq + 2 * PLANE_USH + base)  = o2;
}

// ---------------- prep: cas_K sparse-column table, 1/K folded in ------------
__global__ __launch_bounds__(256) void prep_tab(float* __restrict__ tab) {
  int idx = blockIdx.x * 256 + threadIdx.x;
  if (idx >= 128 * TABST) return;
  int j  = idx / TABST;
  int np = idx - j * TABST;
  float v = 0.0f;
  if (np < KHT) {
    int c = j >> 1, b = j & 1;
    int pp = 32 * c + b;
    float t1  = TPI * (float)np;
    float t2  = t1 * (float)pp;
    float arg = t2 / 2049.0f;
    v = (cosf(arg) + sinf(arg)) * (1.0f / 2049.0f);
  }
  tab[idx] = v;
}

// ---------------- MFMA GEMM + fused cos(atan2) epilogue ---------------------
// BK=64 tiles. Stage only the 64 NORMAL columns of c-chunk d; flip columns are
// derived in-register: flip(mf, k) = normal(63-mf, k-reflected-in-chunk),
// realized as mirror-column ds_read at slab 7-s plus 8-element reversal.
// Waves: wc=0 compute a=x_ht (normal), wc=1 compute b=x_ht_flip (mirror).
__global__ __launch_bounds__(256, 2) void gemm_mfma(const short* __restrict__ Aq,
                                                    const float* __restrict__ x,
                                                    float* __restrict__ cosp,
                                                    float* __restrict__ xh64) {
  __shared__ __align__(16) short lds[3 * 8192 + 3 * 4096];  // As 48KB + Bs 24KB
  short* As = lds;                 // [p*8192 + s*1024 + row*8]
  short* Bs = lds + 24576;         // [p*4096 + s*512  + m*8]
  const int t    = threadIdx.x;
  const int lane = t & 63;
  const int w    = t >> 6;
  const int wr   = w >> 1, wc = w & 1;
  const int bm   = blockIdx.y * 128;
  const int d    = blockIdx.x;             // c-chunk (64 channels)
  const float* xb = x + d * 262144;
  const int m_st = t & 63;                 // staging column
  const int s0   = t >> 6;                 // staging slab base (0..3)

  f32x4 accM[4][4] = {};   // a0*b0 only (large partials)
  f32x4 accL[4][4] = {};   // the 5 small products

  for (int kt = 0; kt < 64; ++kt) {
    // ---- stage A: 48 KB via gl_lds, 12 wave-instructions per wave ----
    #pragma unroll
    for (int i = 0; i < 12; ++i) {
      int q = w * 12 + i;                  // q = p*16 + s*2 + h
      int p = q >> 4, s = (q >> 1) & 7, h = q & 1;
      const short* gp = Aq + (size_t)p * PLANE_USH + (size_t)(kt * 8 + s) * (MPAD * 8)
                        + (size_t)(bm + h * 64 + lane) * 8;
      gl_lds16(gp, &As[p * 8192 + s * 1024 + h * 512]);
    }
    // ---- stage B: normal cols only, 2 groups inline (load->split->write) ----
    #pragma unroll
    for (int g = 0; g < 2; ++g) {
      int s = s0 + 4 * g;
      float vf[8];
      #pragma unroll
      for (int e = 0; e < 8; ++e)
        vf[e] = xb[(kt << 12) + ((8 * s + e) << 6) + m_st];
      short8 p0, p1, p2;
      #pragma unroll
      for (int e = 0; e < 8; ++e) {
        short h0, h1, h2; split3t(vf[e], h0, h1, h2);
        p0[e] = h0; p1[e] = h1; p2[e] = h2;
      }
      int bi = s * 512 + m_st * 8;
      *(short8*)&Bs[bi]        = p0;
      *(short8*)&Bs[4096 + bi] = p1;
      *(short8*)&Bs[8192 + bi] = p2;
    }
    __syncthreads();     // drains gl_lds (vmcnt) + ds_writes (lgkm)

    // ---- compute: 2 MFMA sub-steps of K=32 ----
    #pragma unroll
    for (int u = 0; u < 2; ++u) {
      const int sg = 4 * u + (lane >> 4);
      short8 fa0[4], fa1[4], fa2[4];
      #pragma unroll
      for (int f = 0; f < 4; ++f) {
        int ai = sg * 1024 + (wr * 64 + f * 16 + (lane & 15)) * 8;
        fa0[f] = *(const short8*)&As[ai];
        fa1[f] = *(const short8*)&As[8192 + ai];
        fa2[f] = *(const short8*)&As[16384 + ai];
      }
      short8 fb[4];
      #pragma unroll
      for (int p = 0; p < 3; ++p) {
        #pragma unroll
        for (int f = 0; f < 4; ++f) {
          if (wc == 0) {
            fb[f] = *(const short8*)&Bs[p * 4096 + sg * 512 + (f * 16 + (lane & 15)) * 8];
          } else {
            short8 v = *(const short8*)&Bs[p * 4096 + (7 - sg) * 512
                                           + (63 - (f * 16 + (lane & 15))) * 8];
            i32x4 vi = __builtin_bit_cast(i32x4, v);
            i32x4 wo;
            wo.x = rot16(vi.w); wo.y = rot16(vi.z);
            wo.z = rot16(vi.y); wo.w = rot16(vi.x);
            fb[f] = __builtin_bit_cast(short8, wo);
          }
        }
        if (p == 0) {
          #pragma unroll
          for (int fi = 0; fi < 4; ++fi)
            #pragma unroll
            for (int fj = 0; fj < 4; ++fj) {
              accM[fi][fj] = __builtin_amdgcn_mfma_f32_16x16x32_bf16(fa0[fi], fb[fj], accM[fi][fj], 0, 0, 0);
              accL[fi][fj] = __builtin_amdgcn_mfma_f32_16x16x32_bf16(fa1[fi], fb[fj], accL[fi][fj], 0, 0, 0);
              accL[fi][fj] = __builtin_amdgcn_mfma_f32_16x16x32_bf16(fa2[fi], fb[fj], accL[fi][fj], 0, 0, 0);
            }
        } else if (p == 1) {
          #pragma unroll
          for (int fi = 0; fi < 4; ++fi)
            #pragma unroll
            for (int fj = 0; fj < 4; ++fj) {
              accL[fi][fj] = __builtin_amdgcn_mfma_f32_16x16x32_bf16(fa0[fi], fb[fj], accL[fi][fj], 0, 0, 0);
              accL[fi][fj] = __builtin_amdgcn_mfma_f32_16x16x32_bf16(fa1[fi], fb[fj], accL[fi][fj], 0, 0, 0);
            }
        } else {
          #pragma unroll
          for (int fi = 0; fi < 4; ++fi)
            #pragma unroll
            for (int fj = 0; fj < 4; ++fj)
              accL[fi][fj] = __builtin_amdgcn_mfma_f32_16x16x32_bf16(fa0[fi], fb[fj], accL[fi][fj], 0, 0, 0);
        }
      }
    }
    __syncthreads();     // all waves done reading As/Bs before next stage
  }

  // ---- epilogue: wc=1 publishes b via LDS; wc=0 fuses cos(atan2) ----
  float* bx = (float*)lds;           // 32 KB exchange region (As dead now)
  if (wc) {
    #pragma unroll
    for (int fi = 0; fi < 4; ++fi)
      #pragma unroll
      for (int fj = 0; fj < 4; ++fj)
        #pragma unroll
        for (int r = 0; r < 4; ++r)
          bx[wr * 4096 + (fi * 16 + ((lane >> 4) << 2) + r) * 64 + fj * 16 + (lane & 15)]
            = accM[fi][fj][r] + accL[fi][fj][r];
  }
  __syncthreads();
  if (!wc) {
    #pragma unroll
    for (int fi = 0; fi < 4; ++fi) {
      #pragma unroll
      for (int fj = 0; fj < 4; ++fj) {
        #pragma unroll
        for (int r = 0; r < 4; ++r) {
          int rl = fi * 16 + ((lane >> 4) << 2) + r;
          int cl = fj * 16 + (lane & 15);
          float a = accM[fi][fj][r] + accL[fi][fj][r];
          float b = bx[wr * 4096 + rl * 64 + cl];
          float r2 = a * a + b * b;
          float cp = (r2 > 0.0f) ? (a / sqrtf(r2)) : 1.0f;   // cos(atan2(b,a))
          int row = bm + wr * 64 + rl;
          cosp[(size_t)row * 2048 + d * 64 + cl] = cp;
          if (bm == 0 && wr == 0) xh64[row * 2048 + d * 64 + cl] = a;
        }
      }
    }
  }
}

// ---------------- compl_mul: out_ht[b,o,m], modes=64 ------------------------
__global__ __launch_bounds__(256) void complmul(const float* __restrict__ xh64,
                                                const float* __restrict__ W,
                                                float* __restrict__ oh) {
  __shared__ float cl[64 * 65];
  const int t  = threadIdx.x;
  const int bq = blockIdx.y;
  const int og = blockIdx.x;
  #pragma unroll
  for (int e = 0; e < 16; ++e) {
    int idx = t + e * 256;
    int i = idx & 63, m = idx >> 6;
    cl[m * 65 + i] = xh64[m * 2048 + bq * 64 + i];
  }
  __syncthreads();
  const int m  = t & 63;
  const int o  = og * 4 + (t >> 6);
  const int mn = (64 - m) & 63;
  float s = 0.0f;
  for (int i = 0; i < 64; ++i) {
    float w  = W[i * 4096 + o * 64 + m];
    float wn = W[i * 4096 + o * 64 + mn];
    s += cl[m * 65 + i] * (w + wn) + cl[mn * 65 + i] * (w - wn);
  }
  oh[bq * 4096 + o * 64 + m] = 0.5f * s;
}

// ---------------- final: xi (sparse 64-term) * cosp -------------------------
__global__ __launch_bounds__(256) void final_k(const float* __restrict__ cosp,
                                               const float* __restrict__ tab,
                                               const float* __restrict__ oh,
                                               float* __restrict__ out) {
  __shared__ float tl[128 * 32];
  __shared__ float ol[64 * 64];
  const int t  = threadIdx.x;
  const int d  = blockIdx.y;
  const int n0 = blockIdx.x * 32;
  #pragma unroll
  for (int e = 0; e < 16; ++e) {
    int idx = t + e * 256;
    tl[idx] = tab[(idx >> 5) * TABST + n0 + (idx & 31)];
  }
  #pragma unroll
  for (int e = 0; e < 16; ++e) {
    int idx = t + e * 256;
    ol[idx] = oh[d * 4096 + idx];
  }
  __syncthreads();
  const int mp   = t & 63;
  const int nsub = t >> 6;

  float ohreg[64];
  #pragma unroll
  for (int c = 0; c < 64; ++c)
    ohreg[c] = ol[c * 64 + ((mp - c) & 63)];

  float acc[8] = {};
  #pragma unroll
  for (int c = 0; c < 64; ++c) {
    const float* tp = &tl[(2 * c + (c > mp ? 1 : 0)) * 32 + nsub * 8];
    float tv[8];
    *(float4*)&tv[0] = *(const float4*)tp;
    *(float4*)&tv[4] = *(const float4*)(tp + 4);
    #pragma unroll
    for (int q = 0; q < 8; ++q) acc[q] += tv[q] * ohreg[c];
  }
  #pragma unroll
  for (int q = 0; q < 8; ++q) {
    int np = n0 + nsub * 8 + q;
    if (np < KHT) {
      float cp = cosp[(size_t)np * 2048 + d * 64 + mp];
      out[d * 131136 + mp * 2049 + np] = acc[q] * cp;
    }
  }
}

extern "C" void kernel_launch(void* const* d_in, const int* in_sizes, int n_in,
                              void* d_out, int out_size, void* d_ws, size_t ws_size,
                              hipStream_t stream) {
  const float* x = (const float*)d_in[0];     // (32, 64, 4096) f32
  const float* W = (const float*)d_in[1];     // (64, 64, 64) f32
  float* out = (float*)d_out;                 // (32, 64, 2049) f32
  float* ws  = (float*)d_ws;

  short* Aq    = (short*)ws;
  float* cospB = ws + COSP_OFF;
  float* xh64  = ws + XH_OFF;
  float* tab   = ws + TAB_OFF;
  float* oh    = ws + OH_OFF;

  prep_A   <<<dim3((MPAD + 255) / 256, SLABS), dim3(256), 0, stream>>>(Aq);
  prep_tab <<<dim3((128 * TABST + 255) / 256), dim3(256), 0, stream>>>(tab);
  gemm_mfma<<<dim3(32, 17), dim3(256), 0, stream>>>(Aq, x, cospB, xh64);
  complmul <<<dim3(16, BATCH), dim3(256), 0, stream>>>(xh64, W, oh);
  final_k  <<<dim3(65, BATCH), dim3(256), 0, stream>>>(cospB, tab, oh, out);
}